// Round 6
// baseline (98.704 us; speedup 1.0000x reference)
//
#include <hip/hip_runtime.h>
#include <math.h>

#pragma clang fp contract(off)

#define B_N   8
#define C_N   3
#define H_IMG 720
#define W_IMG 1280
#define GH    4
#define GW    4
#define CELL_H (H_IMG / GH)   // 180
#define CELL_W (W_IMG / GW)   // 320

// ---------------------------------------------------------------------------
// Kernel 1: 128 x (8x8 f32 solve) == netlib sgesv compiled WITHOUT FMA:
// getf2 (first-strict-max pivot, reciprocal scal, mul-sub ger), then
// column-oriented mul-sub forward (unit lower) and DIVIDE backward
// (non-unit upper) substitution. This exact path passed Output 0 in
// rounds 2 & 5 — frozen, do not change any rounding.
// ---------------------------------------------------------------------------
__global__ void hs_kernel(const float* __restrict__ theta, float* __restrict__ Hs) {
#pragma clang fp contract(off)
    int t = threadIdx.x;
    if (t >= B_N * GH * GW) return;
    int b   = t >> 4;
    int rem = t & 15;
    int i   = rem >> 2;
    int j   = rem & 3;

    float hh = (float)i * 0.5f - 1.0f;
    float ww = (float)j * 0.5f - 1.0f;
    float xs4[4] = { ww, ww + 0.5f, ww, ww + 0.5f };
    float ys4[4] = { hh, hh, hh + 0.5f, hh + 0.5f };
    int ci[4] = { i, i, i + 1, i + 1 };
    int cj[4] = { j, j + 1, j, j + 1 };

    float A[8][8], bv[8];
#pragma unroll
    for (int k = 0; k < 4; ++k) {
        int base = ((b * (GH + 1) + ci[k]) * (GW + 1) + cj[k]) * 2;
        float u = theta[base + 0];
        float v = theta[base + 1];
        float x = xs4[k], y = ys4[k];
        A[k][0] = x;    A[k][1] = y;    A[k][2] = 1.0f;
        A[k][3] = 0.0f; A[k][4] = 0.0f; A[k][5] = 0.0f;
        A[k][6] = -x * u;  A[k][7] = -y * u;
        bv[k] = u;
        A[k+4][0] = 0.0f; A[k+4][1] = 0.0f; A[k+4][2] = 0.0f;
        A[k+4][3] = x;    A[k+4][4] = y;    A[k+4][5] = 1.0f;
        A[k+4][6] = -x * v;  A[k+4][7] = -y * v;
        bv[k+4] = v;
    }
#pragma unroll
    for (int d = 0; d < 8; ++d) A[d][d] = A[d][d] + 1e-4f;

    // getf2: LU with partial pivoting (first strict max), reciprocal scal,
    // mul-then-sub trailing update (NO FMA anywhere)
    for (int k = 0; k < 8; ++k) {
        int p = k;
        float pm = fabsf(A[k][k]);
        for (int r = k + 1; r < 8; ++r) {
            float m = fabsf(A[r][k]);
            if (m > pm) { pm = m; p = r; }
        }
        if (p != k) {
            for (int c = 0; c < 8; ++c) {
                float tmp = A[k][c]; A[k][c] = A[p][c]; A[p][c] = tmp;
            }
            float tb = bv[k]; bv[k] = bv[p]; bv[p] = tb;
        }
        float inv = 1.0f / A[k][k];
        for (int r = k + 1; r < 8; ++r) A[r][k] = A[r][k] * inv;
        for (int r = k + 1; r < 8; ++r) {
            float l = A[r][k];
            for (int c = k + 1; c < 8; ++c) A[r][c] = A[r][c] - l * A[k][c];
        }
    }
    // forward substitution: unit lower, column-oriented, mul-sub
    for (int k = 0; k < 8; ++k) {
        float bk = bv[k];
        for (int r = k + 1; r < 8; ++r) bv[r] = bv[r] - bk * A[r][k];
    }
    // backward substitution: non-unit upper, column-oriented, divide
    for (int k = 7; k >= 0; --k) {
        bv[k] = bv[k] / A[k][k];
        float bk = bv[k];
        for (int r = 0; r < k; ++r) bv[r] = bv[r] - bk * A[r][k];
    }

    float* o = Hs + t * 9;
#pragma unroll
    for (int k = 0; k < 8; ++k) o[k] = bv[k];
    o[8] = 1.0f;
}

// ---------------------------------------------------------------------------
// Kernel 2: per-pixel warp — FULL JAX-f32 weak-typing semantics:
//  * grid: jnp.linspace in f32:  g = -1.0f + i * f32(2/(N-1)), endpoint
//    concatenated exactly as 1.0f (jax lax.concatenate of broadcast_stop)
//  * einsum f32, non-FMA, left-assoc over c: (h0*gx + h1*gy) + h2
//  * z-guard, divide, oob, bilinear ALL in f32 (jnp.where(c,1.0,-1.0) stays
//    f32 under jax weak typing — NOT numpy's f64 promotion)
// ---------------------------------------------------------------------------
__global__ __launch_bounds__(256) void warp_kernel(const float* __restrict__ U,
                                                   const float* __restrict__ Hs,
                                                   float* __restrict__ out) {
#pragma clang fp contract(off)
    const int HW = H_IMG * W_IMG;
    int idx = blockIdx.x * 256 + threadIdx.x;
    if (idx >= B_N * HW) return;

    int x = idx % W_IMG;
    int t = idx / W_IMG;
    int y = t % H_IMG;
    int b = t / H_IMG;

    int ci = y / CELL_H;
    int cj = x / CELL_W;
    const float* Hm = Hs + (((b * GH) + ci) * GW + cj) * 9;
    float h0 = Hm[0], h1 = Hm[1], h2 = Hm[2];
    float h3 = Hm[3], h4 = Hm[4], h5 = Hm[5];
    float h6 = Hm[6], h7 = Hm[7];

    // jax linspace f32: delta = f32(2/(N-1)); g = (-1.0f) + i*delta;
    // endpoint row/col replaced by exact stop (1.0f)
    const float DX = 2.0f / 1279.0f;   // f32 correctly-rounded constant
    const float DY = 2.0f / 719.0f;
    float gx = (x == W_IMG - 1) ? 1.0f : (-1.0f + (float)x * DX);
    float gy = (y == H_IMG - 1) ? 1.0f : (-1.0f + (float)y * DY);

    // einsum f32, non-FMA, left-assoc over c
    float X = h0 * gx + h1 * gy + h2;
    float Y = h3 * gx + h4 * gy + h5;
    float Z = h6 * gx + h7 * gy + 1.0f;

    // f32 tail (jax weak typing): guard, divide, oob
    float Zg = Z + ((Z >= 0.0f) ? 1e-8f : -1e-8f);
    float xm = X / Zg;                 // IEEE f32 divide (no fast-math)
    float ym = Y / Zg;

    bool oob = (xm < -1.0f) | (xm > 1.0f) | (ym < -1.0f) | (ym > 1.0f);

    // bilinear, all f32: xf = ((x+1.0)*W)/2.0 left-assoc
    float xf = ((xm + 1.0f) * 1280.0f) * 0.5f;
    float yf = ((ym + 1.0f) * 720.0f) * 0.5f;
    int x0 = (int)floorf(xf);
    int y0 = (int)floorf(yf);
    int x1 = x0 + 1;
    int y1 = y0 + 1;
    x0 = min(max(x0, 0), W_IMG - 1);
    x1 = min(max(x1, 0), W_IMG - 1);
    y0 = min(max(y0, 0), H_IMG - 1);
    y1 = min(max(y1, 0), H_IMG - 1);
    float x0f = (float)x0, x1f = (float)x1;
    float y0f = (float)y0, y1f = (float)y1;
    float wa = (x1f - xf) * (y1f - yf);
    float wb = (x1f - xf) * (yf - y0f);
    float wcw = (xf - x0f) * (y1f - yf);
    float wd = (xf - x0f) * (yf - y0f);

    float* out0 = out;
    float* out1 = out + (size_t)B_N * C_N * HW;
    float* out2 = out1 + (size_t)B_N * HW;
    float* out3 = out2 + (size_t)B_N * HW * 2;
    float* out4 = out3 + (size_t)B_N * HW;

    const float* Ub = U + (size_t)b * C_N * HW;
    int ia = y0 * W_IMG + x0;
    int ib = y1 * W_IMG + x0;
    int ic = y0 * W_IMG + x1;
    int id = y1 * W_IMG + x1;
#pragma unroll
    for (int c = 0; c < C_N; ++c) {
        const float* Uc = Ub + (size_t)c * HW;
        float Ia  = Uc[ia];
        float Ibv = Uc[ib];
        float Icv = Uc[ic];
        float Idv = Uc[id];
        // left-assoc f32, no FMA: ((wa*Ia + wb*Ib) + wc*Ic) + wd*Id
        float val = wa * Ia + wb * Ibv + wcw * Icv + wd * Idv;
        out0[(size_t)(b * C_N + c) * HW + (size_t)y * W_IMG + x] = val;
    }
    out1[idx] = oob ? 1.0f : 0.0f;
    float2 xy; xy.x = xm; xy.y = ym;
    reinterpret_cast<float2*>(out2)[idx] = xy;
    out3[idx] = xm;
    out4[idx] = ym;
}

extern "C" void kernel_launch(void* const* d_in, const int* in_sizes, int n_in,
                              void* d_out, int out_size, void* d_ws, size_t ws_size,
                              hipStream_t stream) {
    const float* U     = (const float*)d_in[0];
    const float* theta = (const float*)d_in[1];
    float* out = (float*)d_out;
    float* Hs  = (float*)d_ws;   // 128 * 9 floats

    hipLaunchKernelGGL(hs_kernel, dim3(1), dim3(128), 0, stream, theta, Hs);

    int total = B_N * H_IMG * W_IMG;
    int blocks = (total + 255) / 256;
    hipLaunchKernelGGL(warp_kernel, dim3(blocks), dim3(256), 0, stream, U, Hs, out);
}